// Round 1
// baseline (114.804 us; speedup 1.0000x reference)
//
#include <hip/hip_runtime.h>
#include <stdint.h>

// Problem constants (fixed by setup_inputs):
//   features (B=128, U=100000) f32; positions (U,2) f32; neighborhoods (NN=100, K=500) i32
//   N_RUNS=10, choice = jax.random.randint(key(42), (10,), 0, 100)  -> computed on host via Threefry
#define U_DIM 100000
#define B_DIM 128
#define K_DIM 500
#define NRUNS 10
#define KPAD  512   // K padded to 8 tiles of 64

struct ChoiceArgs { int c[NRUNS]; };

// ---------------------------------------------------------------------------
// Kernel 1: per (run, neighbor k): gather feature column, normalize (subtract
// batch mean, divide by L2 norm), store to ws. One wave per (r,k); lane b and
// b+64 handle the two halves of the 128-long feature vector.
// Also zeroes the 5*NRUNS double accumulators (block 0).
// ---------------------------------------------------------------------------
__global__ __launch_bounds__(256) void prep_kernel(
    const float* __restrict__ feat, const float* __restrict__ pos,
    const int* __restrict__ neigh, float* __restrict__ xn,
    float2* __restrict__ npos, double* __restrict__ accum, ChoiceArgs ch)
{
  if (blockIdx.x == 0 && threadIdx.x < NRUNS * 5) accum[threadIdx.x] = 0.0;

  int gw   = (blockIdx.x * 256 + threadIdx.x) >> 6;   // global wave id
  int lane = threadIdx.x & 63;
  if (gw >= NRUNS * K_DIM) return;
  int r = gw / K_DIM;
  int k = gw - r * K_DIM;

  int ind = neigh[ch.c[r] * K_DIM + k];
  float f0 = feat[(size_t)lane        * U_DIM + ind];
  float f1 = feat[(size_t)(lane + 64) * U_DIM + ind];

  float s = f0 + f1;
  #pragma unroll
  for (int off = 32; off; off >>= 1) s += __shfl_xor(s, off);
  float mean = s * (1.0f / 128.0f);

  float a0 = f0 - mean, a1 = f1 - mean;
  float q = a0 * a0 + a1 * a1;
  #pragma unroll
  for (int off = 32; off; off >>= 1) q += __shfl_xor(q, off);
  float inv = rsqrtf(q);

  size_t base = ((size_t)r * KPAD + k) * B_DIM;
  xn[base + lane]      = a0 * inv;
  xn[base + lane + 64] = a1 * inv;
  if (lane == 0) npos[r * KPAD + k] = make_float2(pos[2 * ind], pos[2 * ind + 1]);
}

// ---------------------------------------------------------------------------
// Kernel 2: lower-triangle tile pairs. corr[i,j] = xn_i . xn_j. Accumulate the
// 5 Pearson sums (Sa, Sb, Saa, Sbb, Sab) over valid pairs (i>j, i,j<500).
// grid = (36 tile pairs, NRUNS). 256 threads, 4x4 register tile each.
// LDS: A row-major stride 132 (2-way conflicts = free); B transposed [b][j]
// stride 68 (2-way = free on both staging stores and compute reads).
// ---------------------------------------------------------------------------
#define SA 132
#define SB 68

__global__ __launch_bounds__(256) void pair_kernel(
    const float* __restrict__ xn, const float2* __restrict__ npos,
    double* __restrict__ accum)
{
  __shared__ float  ldsA[64 * SA];
  __shared__ float  ldsBT[128 * SB];
  __shared__ float2 posA[64], posB[64];
  __shared__ float  red[4][5];

  int r = blockIdx.y;
  int p = blockIdx.x;                 // p = ti*(ti+1)/2 + tj, ti >= tj
  int ti = 0;
  while ((ti + 1) * (ti + 2) / 2 <= p) ti++;
  int tj = p - ti * (ti + 1) / 2;

  const float*  xr = xn   + (size_t)r * KPAD * B_DIM;
  const float2* pr = npos + r * KPAD;
  int tid = threadIdx.x;

  // stage A tile: [row][b], float4 contiguous (conflict-free stores)
  #pragma unroll
  for (int it = 0; it < 8; it++) {
    int idx = (it * 256 + tid) * 4;
    int row = idx >> 7, col = idx & 127;
    int gi = ti * 64 + row;
    float4 v = (gi < K_DIM) ? *(const float4*)(xr + (size_t)gi * B_DIM + col)
                            : make_float4(0.f, 0.f, 0.f, 0.f);
    *(float4*)(&ldsA[row * SA + col]) = v;
  }
  // stage B tile transposed: ldsBT[b][j]
  {
    int j  = tid & 63;
    int bq = (tid >> 6) * 4;
    int gj = tj * 64 + j;
    bool ok = (gj < K_DIM);
    const float* src = xr + (size_t)(ok ? gj : 0) * B_DIM;
    #pragma unroll
    for (int c = 0; c < 128; c += 16) {
      int b = c + bq;
      float4 f = ok ? *(const float4*)(src + b) : make_float4(0.f, 0.f, 0.f, 0.f);
      ldsBT[(b + 0) * SB + j] = f.x;
      ldsBT[(b + 1) * SB + j] = f.y;
      ldsBT[(b + 2) * SB + j] = f.z;
      ldsBT[(b + 3) * SB + j] = f.w;
    }
  }
  if (tid < 64) {
    int gi = ti * 64 + tid;
    posA[tid] = (gi < K_DIM) ? pr[gi] : make_float2(0.f, 0.f);
  } else if (tid < 128) {
    int j = tid - 64, gj = tj * 64 + j;
    posB[j] = (gj < K_DIM) ? pr[gj] : make_float2(0.f, 0.f);
  }
  __syncthreads();

  int tx = tid & 15, ty = tid >> 4;   // 16 x 16 thread tile, each 4x4 pairs
  float acc[4][4] = {};
  const float* Ap = &ldsA[(ty * 4) * SA];
  const float* Bp = &ldsBT[tx * 4];

  for (int b = 0; b < 128; b += 4) {
    float4 av0 = *(const float4*)(Ap + 0 * SA + b);
    float4 av1 = *(const float4*)(Ap + 1 * SA + b);
    float4 av2 = *(const float4*)(Ap + 2 * SA + b);
    float4 av3 = *(const float4*)(Ap + 3 * SA + b);
    float4 bv0 = *(const float4*)(Bp + (b + 0) * SB);
    float4 bv1 = *(const float4*)(Bp + (b + 1) * SB);
    float4 bv2 = *(const float4*)(Bp + (b + 2) * SB);
    float4 bv3 = *(const float4*)(Bp + (b + 3) * SB);
    float4 av[4] = {av0, av1, av2, av3};
    #pragma unroll
    for (int u = 0; u < 4; ++u) {
      float4 a = av[u];
      acc[u][0] += a.x * bv0.x + a.y * bv1.x + a.z * bv2.x + a.w * bv3.x;
      acc[u][1] += a.x * bv0.y + a.y * bv1.y + a.z * bv2.y + a.w * bv3.y;
      acc[u][2] += a.x * bv0.z + a.y * bv1.z + a.z * bv2.z + a.w * bv3.z;
      acc[u][3] += a.x * bv0.w + a.y * bv1.w + a.z * bv2.w + a.w * bv3.w;
    }
  }

  // per-thread Pearson partial sums over its valid pairs
  float sa = 0.f, sb = 0.f, saa = 0.f, sbb = 0.f, sab = 0.f;
  float2 pa[4], pb[4];
  #pragma unroll
  for (int u = 0; u < 4; u++) pa[u] = posA[ty * 4 + u];
  #pragma unroll
  for (int v = 0; v < 4; v++) pb[v] = posB[tx * 4 + v];
  int gi0 = ti * 64 + ty * 4, gj0 = tj * 64 + tx * 4;
  #pragma unroll
  for (int u = 0; u < 4; u++) {
    #pragma unroll
    for (int v = 0; v < 4; v++) {
      int gi = gi0 + u, gj = gj0 + v;
      if (gi < K_DIM && gj < K_DIM && gi > gj) {
        float resp = acc[u][v];
        float dx = pa[u].x - pb[v].x, dy = pa[u].y - pb[v].y;
        float ds = 1.0f / (sqrtf(dx * dx + dy * dy) + 1.0f);
        sa += resp; sb += ds;
        saa += resp * resp; sbb += ds * ds; sab += resp * ds;
      }
    }
  }
  #pragma unroll
  for (int off = 32; off; off >>= 1) {
    sa  += __shfl_xor(sa,  off);
    sb  += __shfl_xor(sb,  off);
    saa += __shfl_xor(saa, off);
    sbb += __shfl_xor(sbb, off);
    sab += __shfl_xor(sab, off);
  }
  int w = tid >> 6;
  if ((tid & 63) == 0) {
    red[w][0] = sa; red[w][1] = sb; red[w][2] = saa; red[w][3] = sbb; red[w][4] = sab;
  }
  __syncthreads();
  if (tid == 0) {
    #pragma unroll
    for (int i = 0; i < 5; i++) {
      double t = (double)red[0][i] + (double)red[1][i] + (double)red[2][i] + (double)red[3][i];
      atomicAdd(&accum[r * 5 + i], t);
    }
  }
}

// ---------------------------------------------------------------------------
// Kernel 3: per-run Pearson r -> loss -> mean over runs.
// ---------------------------------------------------------------------------
__global__ void finalize_kernel(const double* __restrict__ accum, float* __restrict__ out)
{
  if (threadIdx.x == 0 && blockIdx.x == 0) {
    const double n = (double)(K_DIM * (K_DIM - 1) / 2);   // 124750
    double total = 0.0;
    for (int r = 0; r < NRUNS; r++) {
      double sa = accum[r * 5 + 0], sb = accum[r * 5 + 1];
      double saa = accum[r * 5 + 2], sbb = accum[r * 5 + 3], sab = accum[r * 5 + 4];
      double cov = sab - sa * sb / n;
      double va  = saa - sa * sa / n;
      double vb  = sbb - sb * sb / n;
      double rr  = cov / sqrt(va * vb);
      total += (1.0 - rr) * 0.5;
    }
    out[0] = (float)(total / NRUNS);
  }
}

// ---------------------------------------------------------------------------
// Host: JAX Threefry-2x32 to reproduce choice = randint(key(42), (10,), 0, 100)
// ---------------------------------------------------------------------------
static inline uint32_t rotl32_host(uint32_t x, int r) { return (x << r) | (x >> (32 - r)); }

static void tf2x32(uint32_t k0, uint32_t k1, uint32_t c0, uint32_t c1,
                   uint32_t& o0, uint32_t& o1)
{
  const uint32_t rots[2][4] = {{13, 15, 26, 6}, {17, 29, 16, 24}};
  uint32_t ks[3] = {k0, k1, k0 ^ k1 ^ 0x1BD11BDAu};
  uint32_t x0 = c0 + ks[0], x1 = c1 + ks[1];
  for (int i = 0; i < 5; i++) {
    const uint32_t* rr = rots[i & 1];
    for (int j = 0; j < 4; j++) {
      x0 += x1;
      x1 = rotl32_host(x1, (int)rr[j]);
      x1 ^= x0;
    }
    x0 += ks[(i + 1) % 3];
    x1 += ks[(i + 2) % 3] + (uint32_t)(i + 1);
  }
  o0 = x0; o1 = x1;
}

extern "C" void kernel_launch(void* const* d_in, const int* in_sizes, int n_in,
                              void* d_out, int out_size, void* d_ws, size_t ws_size,
                              hipStream_t stream)
{
  const float* feat  = (const float*)d_in[0];
  const float* pos   = (const float*)d_in[1];
  const int*   neigh = (const int*)d_in[2];
  float* out = (float*)d_out;

  // --- reproduce jax.random.randint(jax.random.key(42), (10,), 0, 100) ---
  // key(42) -> (0, 42); split into k1, k2; counts [0..3] -> pairs (0,2),(1,3)
  ChoiceArgs ch;
  uint32_t A0, B0, A1, B1;
  tf2x32(0u, 42u, 0u, 2u, A0, B0);
  tf2x32(0u, 42u, 1u, 3u, A1, B1);
  // k1 = (A0, A1) -> higher bits; k2 = (B0, B1) -> lower bits
  uint32_t hi[NRUNS], lo[NRUNS];
  for (int e = 0; e < 5; e++) {
    uint32_t h0, h1, l0, l1;
    tf2x32(A0, A1, (uint32_t)e, (uint32_t)(e + 5), h0, h1);
    hi[e] = h0; hi[e + 5] = h1;
    tf2x32(B0, B1, (uint32_t)e, (uint32_t)(e + 5), l0, l1);
    lo[e] = l0; lo[e + 5] = l1;
  }
  // span=100: multiplier = (2^16 % 100)^2 % 100 = 96
  for (int e = 0; e < NRUNS; e++)
    ch.c[e] = (int)(((hi[e] % 100u) * 96u + (lo[e] % 100u)) % 100u);

  // --- workspace layout ---
  char* ws = (char*)d_ws;
  float*  xn    = (float*)ws;                                    // 10*512*128 f32 = 2.62 MB
  float2* npos  = (float2*)(ws + (size_t)NRUNS * KPAD * B_DIM * 4);      // 10*512 float2
  double* accum = (double*)(ws + (size_t)NRUNS * KPAD * B_DIM * 4
                               + (size_t)NRUNS * KPAD * 8);      // 50 doubles

  prep_kernel<<<dim3((NRUNS * K_DIM) / 4), 256, 0, stream>>>(feat, pos, neigh, xn, npos, accum, ch);
  pair_kernel<<<dim3(36, NRUNS), 256, 0, stream>>>(xn, npos, accum);
  finalize_kernel<<<1, 64, 0, stream>>>(accum, out);
}